// Round 5
// baseline (270.124 us; speedup 1.0000x reference)
//
#include <hip/hip_runtime.h>

#define LOG2E 1.4426950408889634f

constexpr int Dn = 128;
constexpr int Nn = 16384;
constexpr int Kn = 64;
constexpr int Bn = 16;

typedef float v2f __attribute__((ext_vector_type(2)));
typedef __attribute__((ext_vector_type(16))) float f32x16;

// Prep: folds mu-normalize, exp(-log_sigma), factor -2, k-constant and log2e.
// Layout v6 (k-pair packed for v_pk_fma_f32): per (kg = k>>4, d) a 32-float
// record: [a(2p), a(2p+1), b(2p), b(2p+1)] for p = 0..7, k = 16kg + 2p + h.
// Two s_load_dwordx16 per (kg,d); every (a,b) pair is even-aligned in the
// SGPR file (offset 4p / 4p+2 within a 4-aligned x16 destination).
__global__ __launch_bounds__(64) void gmm_prep(const float* __restrict__ mu,
                                               const float* __restrict__ log_sigma,
                                               const float* __restrict__ log_alpha,
                                               float* __restrict__ wout,
                                               float* __restrict__ cout) {
    const int k = blockIdx.x;
    const int l = threadIdx.x;        // l covers d0 = 2l, d0+1
    const int d0 = 2 * l;
    float m0 = mu[k * Dn + d0];
    float m1 = mu[k * Dn + d0 + 1];
    float s0 = log_sigma[k * Dn + d0];
    float s1 = log_sigma[k * Dn + d0 + 1];
    float nrm2 = m0 * m0 + m1 * m1;
    float lss = s0 + s1;
    #pragma unroll
    for (int off = 32; off > 0; off >>= 1) {
        nrm2 += __shfl_xor(nrm2, off);
        lss  += __shfl_xor(lss, off);
    }
    const float inv_nrm = 1.0f / fmaxf(sqrtf(nrm2), 1e-12f);
    const float mn0 = m0 * inv_nrm, mn1 = m1 * inv_nrm;
    const float si0 = expf(-s0), si1 = expf(-s1);
    float mt = mn0 * mn0 * si0 + mn1 * mn1 * si1;
    #pragma unroll
    for (int off = 32; off > 0; off >>= 1) mt += __shfl_xor(mt, off);

    const int kg = k >> 4;
    const int p  = (k & 15) >> 1;
    const int h  = k & 1;
    float* rec = wout + ((size_t)kg * Dn + d0) * 32;
    rec[4 * p + h]          = -si0 * LOG2E;               // a at d0
    rec[4 * p + 2 + h]      = 2.0f * mn0 * si0 * LOG2E;   // b at d0
    rec[32 + 4 * p + h]     = -si1 * LOG2E;               // a at d0+1
    rec[32 + 4 * p + 2 + h] = 2.0f * mn1 * si1 * LOG2E;   // b at d0+1
    if (l == 0) cout[k] = (log_alpha[k] - 0.5f * lss - mt) * LOG2E;
}

// Main v6: 512 threads = 8 waves = 4 k-groups x 2 n-halves. Wave (kg, nh)
// owns k in [16kg, 16kg+16) and n-half nh; lane owns 2 consecutive n.
// Rounds 1-4 proved VALU busy-time is pinned at ~70us regardless of load
// scheduling -> the lever is instruction COUNT: v_pk_fma_f32 (2 FMA per
// 2-cyc issue). k-pair packing puts the W operand on an even-aligned SGPR
// pair direct from s_load_dwordx16; the per-n x / x^2 scalar is broadcast
// from a VGPR pair's lo/hi half via op_sel — zero splat temporaries (the
// round-3 scratch disaster). 33 VOP3P per d vs 68 scalar -> issue floor
// 58 -> 29us. n-split across waves halves x L1 redundancy to 4-way (16KB
// per d per CU ~50% of L1) so L1 doesn't become the new cap. acc = 8 pairs
// x 2 n = 16 v2f = 32 VGPRs, asm "+v" pins them in arch VGPRs.
__global__ __launch_bounds__(512)
void gmm_main(const float* __restrict__ x,
              const float* __restrict__ w,
              const float* __restrict__ cks,
              float* __restrict__ out) {
    __shared__ float sRed[4][256];     // 4 KB cross-wave softmax buffer

    const int tid = threadIdx.x;
    const int g = __builtin_amdgcn_readfirstlane(tid >> 6);  // wave id 0..7
    const int kg = g & 3;              // k-group: k in [16kg, 16kg+16)
    const int nh = g >> 2;             // n-half within the 256 window
    const int l = tid & 63;
    const int b = blockIdx.y;
    const int nloc = nh * 128 + 2 * l;
    const size_t nbase = (size_t)blockIdx.x * 256 + nloc;

    // init acc with the per-k constant (folds the epilogue add)
    // acc[p][ns]: v2f over k = (16kg+2p, 16kg+2p+1) at n = nbase + ns
    v2f acc[8][2];
    #pragma unroll
    for (int p = 0; p < 8; ++p) {
        v2f c; c[0] = cks[kg * 16 + 2 * p]; c[1] = cks[kg * 16 + 2 * p + 1];
        acc[p][0] = c; acc[p][1] = c;
    }

    const float* xp = x + (size_t)b * Dn * Nn + nbase;
    const char* wp = (const char*)w + (size_t)kg * (Dn * 32 * 4);  // 16 KB slice

// D = W*bcast(X) + D ; W = even-aligned SGPR pair (a or b for k-pair),
// X = VGPR pair holding (x_n0, x_n1) or (t_n0, t_n1); op_sel picks lo/hi.
// src order: S0=W (the 1 allowed SGPR), S1=X, S2=acc.
#define PK_FMA_LO(A, W, X)                                                   \
    asm("v_pk_fma_f32 %0, %2, %1, %0 op_sel:[0,0,0] op_sel_hi:[1,0,1]"       \
        : "+v"(A) : "v"(X), "s"(W))
#define PK_FMA_HI(A, W, X)                                                   \
    asm("v_pk_fma_f32 %0, %2, %1, %0 op_sel:[0,1,0] op_sel_hi:[1,1,1]"       \
        : "+v"(A) : "v"(X), "s"(W))
// one k-pair (quad Q of WV), both n's of the lane, one d:
#define GMM_P(WV, Q, T, X, AP)                                               \
    {                                                                        \
        v2f wa; wa[0] = WV[4 * (Q)];     wa[1] = WV[4 * (Q) + 1];            \
        v2f wb; wb[0] = WV[4 * (Q) + 2]; wb[1] = WV[4 * (Q) + 3];            \
        PK_FMA_LO(AP[0], wa, T); PK_FMA_LO(AP[0], wb, X);                    \
        PK_FMA_HI(AP[1], wa, T); PK_FMA_HI(AP[1], wb, X);                    \
    }

    #pragma unroll 1
    for (int it = 0; it < Dn / 2; ++it) {
        const v2f x0 = *(const v2f*)(xp);        // d = 2it,   n..n+1
        const v2f x1 = *(const v2f*)(xp + Nn);   // d = 2it+1, n..n+1
        xp += 2 * Nn;

        // 64 floats of W for (kg, 2it..2it+1): w0/w1 = even d, w2/w3 = odd d
        f32x16 w0, w1, w2, w3;
        asm volatile("s_load_dwordx16 %0, %4, 0x0\n\t"
                     "s_load_dwordx16 %1, %4, 0x40\n\t"
                     "s_load_dwordx16 %2, %4, 0x80\n\t"
                     "s_load_dwordx16 %3, %4, 0xC0\n\t"
                     "s_waitcnt lgkmcnt(0)"
                     : "=&s"(w0), "=&s"(w1), "=&s"(w2), "=&s"(w3)
                     : "s"(wp));
        wp += 256;

        const v2f t0 = x0 * x0;                  // v_pk_mul_f32
        const v2f t1 = x1 * x1;

        GMM_P(w0, 0, t0, x0, acc[0]); GMM_P(w0, 1, t0, x0, acc[1]);
        GMM_P(w0, 2, t0, x0, acc[2]); GMM_P(w0, 3, t0, x0, acc[3]);
        GMM_P(w1, 0, t0, x0, acc[4]); GMM_P(w1, 1, t0, x0, acc[5]);
        GMM_P(w1, 2, t0, x0, acc[6]); GMM_P(w1, 3, t0, x0, acc[7]);

        GMM_P(w2, 0, t1, x1, acc[0]); GMM_P(w2, 1, t1, x1, acc[1]);
        GMM_P(w2, 2, t1, x1, acc[2]); GMM_P(w2, 3, t1, x1, acc[3]);
        GMM_P(w3, 0, t1, x1, acc[4]); GMM_P(w3, 1, t1, x1, acc[5]);
        GMM_P(w3, 2, t1, x1, acc[6]); GMM_P(w3, 3, t1, x1, acc[7]);
    }
#undef GMM_P
#undef PK_FMA_LO
#undef PK_FMA_HI

    // ---- softmax: per-wave max over its 16 k, then cross-kg over 4 ----
    v2f mx0 = acc[0][0], mx1 = acc[0][1];
    #pragma unroll
    for (int p = 1; p < 8; ++p) {
        mx0 = __builtin_elementwise_max(mx0, acc[p][0]);
        mx1 = __builtin_elementwise_max(mx1, acc[p][1]);
    }
    float m0 = fmaxf(mx0[0], mx0[1]);
    float m1 = fmaxf(mx1[0], mx1[1]);
    *(float2*)&sRed[kg][nloc] = make_float2(m0, m1);
    __syncthreads();
    #pragma unroll
    for (int q = 0; q < 4; ++q) {
        const float2 mm = *(const float2*)&sRed[q][nloc];
        m0 = fmaxf(m0, mm.x); m1 = fmaxf(m1, mm.y);
    }
    __syncthreads();   // before reusing sRed for sums

    // ---- exp2 + cross-kg sum ----
    float s0 = 0.f, s1 = 0.f;
    #pragma unroll
    for (int p = 0; p < 8; ++p) {
        acc[p][0][0] = __builtin_amdgcn_exp2f(acc[p][0][0] - m0); s0 += acc[p][0][0];
        acc[p][0][1] = __builtin_amdgcn_exp2f(acc[p][0][1] - m0); s0 += acc[p][0][1];
        acc[p][1][0] = __builtin_amdgcn_exp2f(acc[p][1][0] - m1); s1 += acc[p][1][0];
        acc[p][1][1] = __builtin_amdgcn_exp2f(acc[p][1][1] - m1); s1 += acc[p][1][1];
    }
    *(float2*)&sRed[kg][nloc] = make_float2(s0, s1);
    __syncthreads();
    s0 = 0.f; s1 = 0.f;
    #pragma unroll
    for (int q = 0; q < 4; ++q) {
        const float2 ss = *(const float2*)&sRed[q][nloc];
        s0 += ss.x; s1 += ss.y;
    }
    const float r0 = 1.0f / s0, r1 = 1.0f / s1;

    // ---- store: out[b][k][n], k = 16kg + 2p + h, float2 per k ----
    float* op = out + (size_t)(b * Kn + kg * 16) * Nn + nbase;
    #pragma unroll
    for (int p = 0; p < 8; ++p) {
        *(float2*)op = make_float2(acc[p][0][0] * r0, acc[p][1][0] * r1);  // h=0
        op += Nn;
        *(float2*)op = make_float2(acc[p][0][1] * r0, acc[p][1][1] * r1);  // h=1
        op += Nn;
    }
}

extern "C" void kernel_launch(void* const* d_in, const int* in_sizes, int n_in,
                              void* d_out, int out_size, void* d_ws, size_t ws_size,
                              hipStream_t stream) {
    const float* x  = (const float*)d_in[0];
    const float* mu = (const float*)d_in[1];
    const float* ls = (const float*)d_in[2];
    const float* la = (const float*)d_in[3];
    float* out = (float*)d_out;

    float* wbuf = (float*)d_ws;                                   // 64 KB
    float* cbuf = (float*)((char*)d_ws + (size_t)4 * Dn * 32 * sizeof(float));

    gmm_prep<<<dim3(Kn), dim3(64), 0, stream>>>(mu, ls, la, wbuf, cbuf);
    gmm_main<<<dim3(Nn / 256, Bn), dim3(512), 0, stream>>>(x, wbuf, cbuf, out);
}

// Round 6
// 221.887 us; speedup vs baseline: 1.2174x; 1.2174x over previous
//
#include <hip/hip_runtime.h>

#define LOG2E 1.4426950408889634f

constexpr int Dn = 128;
constexpr int Nn = 16384;
constexpr int Kn = 64;
constexpr int Bn = 16;

typedef float f32x4 __attribute__((ext_vector_type(4)));
typedef unsigned int u32x4 __attribute__((ext_vector_type(4)));

// round-to-nearest-even bf16, returned as fp32 bits with low 16 zeroed
__device__ __forceinline__ unsigned int rnhi(float f) {
    unsigned int u = __float_as_uint(f);
    return (u + 0x7FFFu + ((u >> 16) & 1u)) & 0xFFFF0000u;
}

// Prep: folds mu-normalize, exp(-log_sigma), factor -2, k-constant, log2e —
// then SPLITS each coefficient into bf16 hi+lo (RNE) and writes MFMA A-frags.
// Frag layout (ushort): wfrag[(((ks*4+s)*4+mat)*64+lane)*8+j], mat 0..3 =
// {a_hi, a_lo, b_hi, b_lo}; lane = (h<<4)|(k&15); d = s*32 + 8h + j.
// The SAME (h,j)->d map is used for the X (B-operand) frags in gmm_main, so
// any hardware permutation of the MFMA contraction slots cancels.
__global__ __launch_bounds__(64) void gmm_prep(const float* __restrict__ mu,
                                               const float* __restrict__ log_sigma,
                                               const float* __restrict__ log_alpha,
                                               unsigned short* __restrict__ wfrag,
                                               float* __restrict__ cout) {
    const int k = blockIdx.x;
    const int l = threadIdx.x;        // covers d0 = 2l, d0+1
    const int d0 = 2 * l;
    float m0 = mu[k * Dn + d0];
    float m1 = mu[k * Dn + d0 + 1];
    float s0 = log_sigma[k * Dn + d0];
    float s1 = log_sigma[k * Dn + d0 + 1];
    float nrm2 = m0 * m0 + m1 * m1;
    float lss = s0 + s1;
    #pragma unroll
    for (int off = 32; off > 0; off >>= 1) {
        nrm2 += __shfl_xor(nrm2, off);
        lss  += __shfl_xor(lss, off);
    }
    const float inv_nrm = 1.0f / fmaxf(sqrtf(nrm2), 1e-12f);
    const float mn0 = m0 * inv_nrm, mn1 = m1 * inv_nrm;
    const float si0 = expf(-s0), si1 = expf(-s1);
    float mt = mn0 * mn0 * si0 + mn1 * mn1 * si1;
    #pragma unroll
    for (int off = 32; off > 0; off >>= 1) mt += __shfl_xor(mt, off);

    const float av[2] = {-si0 * LOG2E, -si1 * LOG2E};
    const float bv[2] = {2.0f * mn0 * si0 * LOG2E, 2.0f * mn1 * si1 * LOG2E};
    const int ks = k >> 4;
    #pragma unroll
    for (int dd = 0; dd < 2; ++dd) {
        const int d = d0 + dd;
        const unsigned int ah = rnhi(av[dd]);
        const unsigned int al = rnhi(av[dd] - __uint_as_float(ah));
        const unsigned int bh = rnhi(bv[dd]);
        const unsigned int bl = rnhi(bv[dd] - __uint_as_float(bh));
        const int s = d >> 5, h = (d >> 3) & 3, j = d & 7;
        const int lane = (h << 4) | (k & 15);
        const size_t base = ((size_t)((ks * 4 + s) * 4) * 64 + lane) * 8 + j;
        wfrag[base + 0 * 64 * 8] = (unsigned short)(ah >> 16);
        wfrag[base + 1 * 64 * 8] = (unsigned short)(al >> 16);
        wfrag[base + 2 * 64 * 8] = (unsigned short)(bh >> 16);
        wfrag[base + 3 * 64 * 8] = (unsigned short)(bl >> 16);
    }
    if (l == 0) cout[k] = (log_alpha[k] - 0.5f * lss - mt) * LOG2E;
}

// Main v7: MFMA. Rounds 1-5 proved the fp32 VALU floor (~58us issue + ~40us
// exposed latency, pk_fma is half-rate) — the matrix pipe (MfmaUtil=0 all
// rounds) is the only unused 2.5PF resource. dist as 2 GEMMs with split-bf16
// (hi+lo, RNE): 6 MFMA terms (ah*th, al*th, ah*tl, bh*xh, bl*xh, bh*xl);
// dropped lo*lo ~ 2^-18 relative. Block = 512 thr / 8 waves, 64 tokens x
// all 64 k. Wave (ks=w&3, tp=w>>2): k-strip 16ks..+15, token-tiles
// {2tp, 2tp+1}. Staging: lane=token -> coalesced global dword reads, split,
// pack, ONE ds_write_b128 per mat per 8-d oct. Main loop: plain C++
// ds_read_b128 of X frags + inline-asm v_mfma (compiler owns all waitcnts).
// C/D: col=lane&15 (token), row=(l>>4)*4+reg (k) [m89-verified].
__global__ __launch_bounds__(512)
__attribute__((amdgpu_waves_per_eu(4, 4)))
void gmm_main(const float* __restrict__ x,
              const unsigned short* __restrict__ wf,
              const float* __restrict__ cks,
              float* __restrict__ out) {
    __shared__ unsigned short sB[4][4][4][64][8];  // [mat][s][tt][lane][j] 64KB
    __shared__ float sRedM[4][64];                 // per-ks token maxes
    __shared__ float sRedS[4][64];                 // per-ks token sums

    const int tid = threadIdx.x;
    const int l = tid & 63;
    const int b = blockIdx.y;
    const int nwin = blockIdx.x * 64;
    const float* xwin = x + (size_t)b * Dn * Nn + nwin;

    // ---- staging: 2 tasks/thread, task = (token tk=l, d-oct o) ----
    float xv[2][8];
    #pragma unroll
    for (int i = 0; i < 2; ++i) {
        const int o = (tid >> 6) + 8 * i;
        #pragma unroll
        for (int jj = 0; jj < 8; ++jj)
            xv[i][jj] = xwin[(size_t)(o * 8 + jj) * Nn + l];
    }
    #pragma unroll
    for (int i = 0; i < 2; ++i) {
        const int o = (tid >> 6) + 8 * i;
        const int s = o >> 2, h = o & 3;
        const int lane = (h << 4) | (l & 15), tt = l >> 4;
        unsigned int XH[4], XL[4], TH[4], TL[4];
        #pragma unroll
        for (int p = 0; p < 4; ++p) {
            const float x0 = xv[i][2 * p], x1 = xv[i][2 * p + 1];
            const float t0 = x0 * x0, t1 = x1 * x1;
            const unsigned int xh0 = rnhi(x0), xh1 = rnhi(x1);
            const unsigned int xq0 = rnhi(x0 - __uint_as_float(xh0));
            const unsigned int xq1 = rnhi(x1 - __uint_as_float(xh1));
            const unsigned int th0 = rnhi(t0), th1 = rnhi(t1);
            const unsigned int tq0 = rnhi(t0 - __uint_as_float(th0));
            const unsigned int tq1 = rnhi(t1 - __uint_as_float(th1));
            XH[p] = (xh0 >> 16) | xh1;   // elem j=2p in lo half, 2p+1 in hi
            XL[p] = (xq0 >> 16) | xq1;
            TH[p] = (th0 >> 16) | th1;
            TL[p] = (tq0 >> 16) | tq1;
        }
        *(u32x4*)&sB[0][s][tt][lane][0] = u32x4{XH[0], XH[1], XH[2], XH[3]};
        *(u32x4*)&sB[1][s][tt][lane][0] = u32x4{XL[0], XL[1], XL[2], XL[3]};
        *(u32x4*)&sB[2][s][tt][lane][0] = u32x4{TH[0], TH[1], TH[2], TH[3]};
        *(u32x4*)&sB[3][s][tt][lane][0] = u32x4{TL[0], TL[1], TL[2], TL[3]};
    }

    // W A-frags: 16 x dwordx4 (overlaps staging latency)
    const int wid = __builtin_amdgcn_readfirstlane(tid >> 6);
    const int ks = wid & 3, tp = wid >> 2;
    u32x4 W[4][4];
    #pragma unroll
    for (int s = 0; s < 4; ++s)
        #pragma unroll
        for (int m = 0; m < 4; ++m)
            W[s][m] = *(const u32x4*)(wf + ((size_t)((ks * 4 + s) * 4 + m) * 64 + l) * 8);

    // acc init with per-k constant (folds epilogue add)
    f32x4 acc[2];
    #pragma unroll
    for (int tt = 0; tt < 2; ++tt)
        #pragma unroll
        for (int r = 0; r < 4; ++r)
            acc[tt][r] = cks[ks * 16 + (l >> 4) * 4 + r];

    __syncthreads();

#define MFMA(C, A, B_) asm("v_mfma_f32_16x16x32_bf16 %0, %1, %2, %0" \
                           : "+v"(C) : "v"(A), "v"(B_))
    asm volatile("s_nop 1");   // VALU-write -> MFMA srcC hazard guard
    #pragma unroll
    for (int s = 0; s < 4; ++s) {
        #pragma unroll
        for (int tt = 0; tt < 2; ++tt) {
            const int ttg = tp * 2 + tt;
            const u32x4 Xh = *(const u32x4*)&sB[0][s][ttg][l][0];
            const u32x4 Xl = *(const u32x4*)&sB[1][s][ttg][l][0];
            const u32x4 Th = *(const u32x4*)&sB[2][s][ttg][l][0];
            const u32x4 Tl = *(const u32x4*)&sB[3][s][ttg][l][0];
            MFMA(acc[tt], W[s][0], Th);   // a_hi * t_hi
            MFMA(acc[tt], W[s][1], Th);   // a_lo * t_hi
            MFMA(acc[tt], W[s][0], Tl);   // a_hi * t_lo
            MFMA(acc[tt], W[s][2], Xh);   // b_hi * x_hi
            MFMA(acc[tt], W[s][3], Xh);   // b_lo * x_hi
            MFMA(acc[tt], W[s][2], Xl);   // b_hi * x_lo
        }
    }
#undef MFMA
    asm volatile("s_nop 7\n\ts_nop 7");   // MFMA-write -> VALU-read hazard

    // ---- softmax: per-wave (16 k) max -> cross-ks via LDS ----
    float mw[2];
    #pragma unroll
    for (int tt = 0; tt < 2; ++tt) {
        float m = fmaxf(fmaxf(acc[tt][0], acc[tt][1]),
                        fmaxf(acc[tt][2], acc[tt][3]));
        m = fmaxf(m, __shfl_xor(m, 16));
        m = fmaxf(m, __shfl_xor(m, 32));
        mw[tt] = m;
        if (l < 16) sRedM[ks][(tp * 2 + tt) * 16 + l] = m;
    }
    __syncthreads();
    float M[2], stot[2];
    #pragma unroll
    for (int tt = 0; tt < 2; ++tt) {
        const int ttg = tp * 2 + tt;
        float m = sRedM[0][ttg * 16 + (l & 15)];
        m = fmaxf(m, sRedM[1][ttg * 16 + (l & 15)]);
        m = fmaxf(m, sRedM[2][ttg * 16 + (l & 15)]);
        m = fmaxf(m, sRedM[3][ttg * 16 + (l & 15)]);
        M[tt] = m;
        float ssum = 0.f;
        #pragma unroll
        for (int r = 0; r < 4; ++r) {
            acc[tt][r] = __builtin_amdgcn_exp2f(acc[tt][r] - m);
            ssum += acc[tt][r];
        }
        ssum += __shfl_xor(ssum, 16);
        ssum += __shfl_xor(ssum, 32);
        if (l < 16) sRedS[ks][ttg * 16 + l] = ssum;
    }
    __syncthreads();
    #pragma unroll
    for (int tt = 0; tt < 2; ++tt) {
        const int ttg = tp * 2 + tt;
        stot[tt] = sRedS[0][ttg * 16 + (l & 15)] + sRedS[1][ttg * 16 + (l & 15)] +
                   sRedS[2][ttg * 16 + (l & 15)] + sRedS[3][ttg * 16 + (l & 15)];
    }

    // ---- store: out[b][ks*16 + (l>>4)*4 + r][nwin + ttg*16 + (l&15)] ----
    #pragma unroll
    for (int tt = 0; tt < 2; ++tt) {
        const int ttg = tp * 2 + tt;
        const float inv = 1.0f / stot[tt];
        float* op = out + ((size_t)(b * Kn + ks * 16 + (l >> 4) * 4)) * Nn +
                    nwin + ttg * 16 + (l & 15);
        #pragma unroll
        for (int r = 0; r < 4; ++r) {
            *op = acc[tt][r] * inv;
            op += Nn;
        }
    }
}

extern "C" void kernel_launch(void* const* d_in, const int* in_sizes, int n_in,
                              void* d_out, int out_size, void* d_ws, size_t ws_size,
                              hipStream_t stream) {
    const float* x  = (const float*)d_in[0];
    const float* mu = (const float*)d_in[1];
    const float* ls = (const float*)d_in[2];
    const float* la = (const float*)d_in[3];
    float* out = (float*)d_out;

    unsigned short* wbuf = (unsigned short*)d_ws;                 // 64 KB frags
    float* cbuf = (float*)((char*)d_ws + 65536);                  // 64 consts

    gmm_prep<<<dim3(Kn), dim3(64), 0, stream>>>(mu, ls, la, wbuf, cbuf);
    gmm_main<<<dim3(Nn / 64, Bn), dim3(512), 0, stream>>>(x, wbuf, cbuf, out);
}